// Round 4
// baseline (463.702 us; speedup 1.0000x reference)
//
#include <hip/hip_runtime.h>

typedef __attribute__((ext_vector_type(8))) short v8s;
typedef __attribute__((ext_vector_type(8))) _Float16 f16x8;
typedef __attribute__((ext_vector_type(4))) _Float16 f16x4;
typedef __attribute__((ext_vector_type(4))) float f32x4;
typedef unsigned short u16;

#define MFMAH(a,b,c) __builtin_amdgcn_mfma_f32_16x16x32_f16((a),(b),(c),0,0,0)
#define L2E 1.4426950408889634f

__device__ __forceinline__ u16 f2h(float f) {
    _Float16 h = (_Float16)f;
    return __builtin_bit_cast(u16, h);
}

__device__ __forceinline__ void gload16(const u16* g, u16* l) {
    __builtin_amdgcn_global_load_lds((const __attribute__((address_space(1))) void*)g,
                                     (__attribute__((address_space(3))) void*)l, 16, 0, 0);
}

// Stage a 128x64 f16 tile (row stride 1024 elems) into LDS.
// LDS dest is linear (gload_lds writes base+lane*16); the XOR slot-swizzle
// (slot' = slot ^ (row&7)) is applied by permuting the per-lane GLOBAL source
// (G21: both-sides-or-neither). Wave w stages rows [32w, 32w+32).
__device__ __forceinline__ void stage_tile(const u16* __restrict__ base, u16* lds, int w, int lane) {
    const int rsub = lane >> 3;
    const int s_org = (lane & 7) ^ rsub;
#pragma unroll
    for (int i = 0; i < 4; ++i) {
        const u16* src = base + (size_t)(32 * w + 8 * i + rsub) * 1024 + 8 * s_org;
        gload16(src, lds + (32 * w + 8 * i) * 64);
    }
}

// Stage a 64x64 f16 tile (arbitrary row stride) into LDS with the same
// XOR slot-swizzle via pre-swizzled global source. Wave w stages rows [16w,16w+16).
__device__ __forceinline__ void stage64(const u16* __restrict__ base, size_t rstride,
                                        u16* lds, int w, int lane) {
    const int rsub = lane >> 3;
    const int s_org = (lane & 7) ^ rsub;
#pragma unroll
    for (int i = 0; i < 2; ++i) {
        const u16* src = base + (size_t)(16 * w + 8 * i + rsub) * rstride + 8 * s_org;
        gload16(src, lds + (16 * w + 8 * i) * 64);
    }
}

// ---------------- elementwise converts ----------------
__global__ __launch_bounds__(256) void split16_kernel(const float* __restrict__ in,
                                                      u16* __restrict__ hi, u16* __restrict__ lo, int n4) {
    int i = blockIdx.x * 256 + threadIdx.x;
    if (i >= n4) return;
    f32x4 v = ((const f32x4*)in)[i];
    f16x4 h, l;
#pragma unroll
    for (int j = 0; j < 4; ++j) {
        _Float16 hh = (_Float16)v[j];
        h[j] = hh;
        l[j] = (_Float16)(v[j] - (float)hh);
    }
    ((f16x4*)hi)[i] = h;
    ((f16x4*)lo)[i] = l;
}

__global__ __launch_bounds__(256) void cvt16_kernel(const float* __restrict__ in, u16* __restrict__ out, int n4) {
    int i = blockIdx.x * 256 + threadIdx.x;
    if (i >= n4) return;
    f32x4 v = ((const f32x4*)in)[i];
    f16x4 h;
#pragma unroll
    for (int j = 0; j < 4; ++j) h[j] = (_Float16)v[j];
    ((f16x4*)out)[i] = h;
}

// ---------------- qkv GEMM: (8192x1024) x (3072x1024)^T ----------------
// q,k columns: acc = xh*w + xl*w (exact-x * fp16-w). v columns: xh*w only.
__global__ __launch_bounds__(256) void qkv_gemm2(const u16* __restrict__ xh, const u16* __restrict__ xl,
                                                 const u16* __restrict__ wf, float* __restrict__ qkv) {
    __shared__ u16 sAh[8192], sAl[8192], sB[8192];
    const int bid = blockIdx.x;
    const int swz = (bid & 7) * 192 + (bid >> 3);   // 1536 = 8*192, bijective XCD swizzle
    const int mb = swz / 24, nb = swz % 24;
    const int m0 = mb * 128, n0 = nb * 128;
    const bool lo = (nb < 16);                      // q,k thirds get the lo term
    const int tid = threadIdx.x, lane = tid & 63, w = tid >> 6;
    const int wr = w >> 1, wc = w & 1;
    const int fr = lane & 15, fq = lane >> 4;
    const u16* pa = xh + (size_t)m0 * 1024;
    const u16* pal = xl + (size_t)m0 * 1024;
    const u16* pb = wf + (size_t)n0 * 1024;
    f32x4 acc[4][4] = {};
    for (int k0 = 0; k0 < 1024; k0 += 64) {
        stage_tile(pa + k0, sAh, w, lane);
        stage_tile(pb + k0, sB, w, lane);
        if (lo) stage_tile(pal + k0, sAl, w, lane);
        __syncthreads();
#pragma unroll
        for (int kk = 0; kk < 2; ++kk) {
            f16x8 ah[4], al[4], bb[4];
#pragma unroll
            for (int m = 0; m < 4; ++m) {
                int row = wr * 64 + m * 16 + fr;
                int off = row * 64 + ((((kk * 4 + fq)) ^ (fr & 7)) << 3);
                ah[m] = *(const f16x8*)&sAh[off];
                if (lo) al[m] = *(const f16x8*)&sAl[off];
            }
#pragma unroll
            for (int n = 0; n < 4; ++n) {
                int row = wc * 64 + n * 16 + fr;
                bb[n] = *(const f16x8*)&sB[row * 64 + ((((kk * 4 + fq)) ^ (fr & 7)) << 3)];
            }
#pragma unroll
            for (int n = 0; n < 4; ++n)
#pragma unroll
                for (int m = 0; m < 4; ++m) {
                    acc[m][n] = MFMAH(ah[m], bb[n], acc[m][n]);
                    if (lo) acc[m][n] = MFMAH(al[m], bb[n], acc[m][n]);
                }
        }
        __syncthreads();
    }
#pragma unroll
    for (int m = 0; m < 4; ++m) {
        int rowb = m0 + wr * 64 + m * 16 + fq * 4;
#pragma unroll
        for (int n = 0; n < 4; ++n) {
            int col = n0 + wc * 64 + n * 16 + fr;
#pragma unroll
            for (int r = 0; r < 4; ++r)
                qkv[(size_t)(rowb + r) * 3072 + col] = acc[m][n][r];
        }
    }
}

// ---------------- rotary (cos/sin of q), fp16 outputs, transpose v ----------------
__global__ __launch_bounds__(256) void rotary_kernel(const float* __restrict__ qkv,
                                                     u16* __restrict__ qf, u16* __restrict__ kf,
                                                     u16* __restrict__ vt) {
    int rid = blockIdx.x * 4 + (threadIdx.x >> 6);
    int lane = threadIdx.x & 63;
    int b = rid >> 14, h = (rid >> 10) & 15, t = rid & 1023;
    const float* base = qkv + (size_t)(b * 1024 + t) * 3072 + h * 64 + lane;
    float q = base[0], k = base[1024], v = base[2048];
    float s, c;
    sincosf(q, &s, &c);
    int src = (lane < 32) ? (2 * lane + 1) : (2 * lane - 64);
    float qp = __shfl(q, src);
    float kp = __shfl(k, src);
    float rq = (lane < 32) ? -qp : qp;
    float rk = (lane < 32) ? -kp : kp;
    float q2 = q * c + rq * s;
    float k2 = k * c + rk * s;
    size_t oi = (size_t)((b * 16 + h) * 1024 + t) * 64 + lane;
    qf[oi] = f2h(q2);
    kf[oi] = f2h(k2);
    vt[(size_t)((b * 16 + h) * 64 + lane) * 1024 + t] = f2h(v);
}

// ---------------- flash attention, causal, scale=1.0, fp16, paired q-tiles ----------------
// One K/V-tile step for one q-tile: QK^T -> online softmax update -> P -> PV.
__device__ __forceinline__ void attn_step(const f16x8* qfr, f32x4* accy, float* m_r, float* l_r,
                                          const u16* sK, const u16* sV, u16* sP,
                                          bool diag, int w, int lane) {
    const int fr = lane & 15, fq = lane >> 4;
    f32x4 s[4] = {};
#pragma unroll
    for (int n = 0; n < 4; ++n) {
        int krow = n * 16 + fr;
#pragma unroll
        for (int kk = 0; kk < 2; ++kk) {
            int sl = kk * 4 + fq;
            f16x8 kb = *(const f16x8*)&sK[krow * 64 + ((sl ^ (krow & 7)) << 3)];
            s[n] = MFMAH(qfr[kk], kb, s[n]);
        }
    }
    if (diag) {
        int rowb = w * 16 + fq * 4;
#pragma unroll
        for (int n = 0; n < 4; ++n)
#pragma unroll
            for (int r = 0; r < 4; ++r)
                if (n * 16 + fr > rowb + r) s[n][r] = -1e30f;
    }
    float alpha[4];
#pragma unroll
    for (int r = 0; r < 4; ++r) {
        float mx = fmaxf(fmaxf(s[0][r], s[1][r]), fmaxf(s[2][r], s[3][r]));
        mx = fmaxf(mx, __shfl_xor(mx, 1));
        mx = fmaxf(mx, __shfl_xor(mx, 2));
        mx = fmaxf(mx, __shfl_xor(mx, 4));
        mx = fmaxf(mx, __shfl_xor(mx, 8));
        float mn = fmaxf(m_r[r], mx);
        alpha[r] = exp2f((m_r[r] - mn) * L2E);
        m_r[r] = mn;
        float rs = 0.f;
#pragma unroll
        for (int n = 0; n < 4; ++n) {
            float p = exp2f((s[n][r] - mn) * L2E);
            s[n][r] = p;
            rs += p;
        }
        rs += __shfl_xor(rs, 1);
        rs += __shfl_xor(rs, 2);
        rs += __shfl_xor(rs, 4);
        rs += __shfl_xor(rs, 8);
        l_r[r] = l_r[r] * alpha[r] + rs;
    }
#pragma unroll
    for (int dn = 0; dn < 4; ++dn)
#pragma unroll
        for (int r = 0; r < 4; ++r) accy[dn][r] *= alpha[r];
    {
        int rowb = w * 16 + fq * 4;
#pragma unroll
        for (int n = 0; n < 4; ++n) {
            int key = n * 16 + fr;
            int s8 = key >> 3, kr = key & 7;
#pragma unroll
            for (int r = 0; r < 4; ++r) {
                int row = rowb + r;
                sP[row * 64 + (((s8 ^ (row & 7)) << 3) | kr)] = f2h(s[n][r]);
            }
        }
    }
    // P rows written & read by the same wave only: no barrier needed.
    f16x8 pa[2];
    {
        int prow = w * 16 + fr;
#pragma unroll
        for (int kk = 0; kk < 2; ++kk) {
            int sl = kk * 4 + fq;
            pa[kk] = *(const f16x8*)&sP[prow * 64 + ((sl ^ (prow & 7)) << 3)];
        }
    }
#pragma unroll
    for (int dn = 0; dn < 4; ++dn) {
        int vrow = dn * 16 + fr;
#pragma unroll
        for (int kk = 0; kk < 2; ++kk) {
            int sl = kk * 4 + fq;
            f16x8 vb = *(const f16x8*)&sV[vrow * 64 + ((sl ^ (vrow & 7)) << 3)];
            accy[dn] = MFMAH(pa[kk], vb, accy[dn]);
        }
    }
}

// Block = (bh, slot): q-tiles qtA = 15-slot and qtB = slot share one K/V loop.
// Per-block MFMA work = 17 tile-steps (constant) -> balanced grid of 1024 blocks.
__global__ __launch_bounds__(256, 4) void attn2_kernel(const u16* __restrict__ qf, const u16* __restrict__ kf,
                                                       const u16* __restrict__ vt, u16* __restrict__ yb) {
    __shared__ u16 sK[4096], sV[4096], sQP[4096];   // sQP: Q staging in prologue, P scratch in loop
    const int bh = blockIdx.x >> 3, slot = blockIdx.x & 7;
    const int b = bh >> 4, h = bh & 15;
    const int qtA = 15 - slot, qtB = slot;
    const int tid = threadIdx.x, lane = tid & 63, w = tid >> 6;
    const int fr = lane & 15, fq = lane >> 4;

    // Prologue: stage both Q tiles (A->sK, B->sV), read frags to registers.
    stage64(qf + (size_t)bh * 65536 + qtA * 4096, 64, sK, w, lane);
    stage64(qf + (size_t)bh * 65536 + qtB * 4096, 64, sV, w, lane);
    __syncthreads();
    f16x8 qfrA[2], qfrB[2];
    {
        int row = w * 16 + fr;
#pragma unroll
        for (int kk = 0; kk < 2; ++kk) {
            int sl = kk * 4 + fq;
            int off = row * 64 + ((sl ^ (row & 7)) << 3);
            qfrA[kk] = *(const f16x8*)&sK[off];
            qfrB[kk] = *(const f16x8*)&sV[off];
        }
    }
    f32x4 accyA[4] = {}, accyB[4] = {};
    float mA[4], lA[4], mB[4], lB[4];
#pragma unroll
    for (int r = 0; r < 4; ++r) { mA[r] = mB[r] = -1e30f; lA[r] = lB[r] = 0.f; }
    const u16* kbase = kf + (size_t)bh * 65536;
    const u16* vbase = vt + (size_t)bh * 65536;

    for (int kt = 0; kt <= qtA; ++kt) {
        __syncthreads();                      // prior reads of sK/sV done (incl. prologue)
        stage64(kbase + kt * 4096, 64, sK, w, lane);
        stage64(vbase + kt * 64, 1024, sV, w, lane);
        __syncthreads();                      // staging visible
        attn_step(qfrA, accyA, mA, lA, sK, sV, sQP, kt == qtA, w, lane);
        if (kt <= qtB)
            attn_step(qfrB, accyB, mB, lB, sK, sV, sQP, kt == qtB, w, lane);
    }
    {
        int rowbase = w * 16 + fq * 4;
        int colb = h * 64 + fr;
#pragma unroll
        for (int r = 0; r < 4; ++r) {
            float invA = 1.0f / lA[r];
            float invB = 1.0f / lB[r];
            int rowA = qtA * 64 + rowbase + r;
            int rowB = qtB * 64 + rowbase + r;
#pragma unroll
            for (int dn = 0; dn < 4; ++dn) {
                yb[(size_t)(b * 1024 + rowA) * 1024 + colb + dn * 16] = f2h(accyA[dn][r] * invA);
                yb[(size_t)(b * 1024 + rowB) * 1024 + colb + dn * 16] = f2h(accyB[dn][r] * invB);
            }
        }
    }
}

// ---------------- out projection: (8192x1024) x (1024x1024)^T, fp16 ----------------
__global__ __launch_bounds__(256) void proj_gemm2(const u16* __restrict__ yb, const u16* __restrict__ wpb,
                                                  float* __restrict__ out) {
    __shared__ u16 sA[8192], sB[8192];
    const int bid = blockIdx.x;
    const int swz = (bid & 7) * 64 + (bid >> 3);    // 512 = 8*64
    const int mb = swz >> 3, nb = swz & 7;
    const int m0 = mb * 128, n0 = nb * 128;
    const int tid = threadIdx.x, lane = tid & 63, w = tid >> 6;
    const int wr = w >> 1, wc = w & 1;
    const int fr = lane & 15, fq = lane >> 4;
    const u16* pa = yb + (size_t)m0 * 1024;
    const u16* pb = wpb + (size_t)n0 * 1024;
    f32x4 acc[4][4] = {};
    for (int k0 = 0; k0 < 1024; k0 += 64) {
        stage_tile(pa + k0, sA, w, lane);
        stage_tile(pb + k0, sB, w, lane);
        __syncthreads();
#pragma unroll
        for (int kk = 0; kk < 2; ++kk) {
            f16x8 af[4], bb[4];
#pragma unroll
            for (int m = 0; m < 4; ++m) {
                int row = wr * 64 + m * 16 + fr;
                af[m] = *(const f16x8*)&sA[row * 64 + ((((kk * 4 + fq)) ^ (fr & 7)) << 3)];
            }
#pragma unroll
            for (int n = 0; n < 4; ++n) {
                int row = wc * 64 + n * 16 + fr;
                bb[n] = *(const f16x8*)&sB[row * 64 + ((((kk * 4 + fq)) ^ (fr & 7)) << 3)];
            }
#pragma unroll
            for (int n = 0; n < 4; ++n)
#pragma unroll
                for (int m = 0; m < 4; ++m) acc[m][n] = MFMAH(af[m], bb[n], acc[m][n]);
        }
        __syncthreads();
    }
#pragma unroll
    for (int m = 0; m < 4; ++m) {
        int rowb = m0 + wr * 64 + m * 16 + fq * 4;
#pragma unroll
        for (int n = 0; n < 4; ++n) {
            int col = n0 + wc * 64 + n * 16 + fr;
#pragma unroll
            for (int r = 0; r < 4; ++r) out[(size_t)(rowb + r) * 1024 + col] = acc[m][n][r];
        }
    }
}

extern "C" void kernel_launch(void* const* d_in, const int* in_sizes, int n_in,
                              void* d_out, int out_size, void* d_ws, size_t ws_size,
                              hipStream_t stream) {
    const float* x  = (const float*)d_in[0];
    const float* Wa = (const float*)d_in[1];
    const float* Wp = (const float*)d_in[2];
    float* out = (float*)d_out;
    char* ws = (char*)d_ws;
    size_t off = 0;
    float* qkv = (float*)(ws + off); off += (size_t)8192 * 3072 * 4;   // 96 MB
    u16* xh  = (u16*)(ws + off); off += 16777216;
    u16* xl  = (u16*)(ws + off); off += 16777216;
    u16* wf  = (u16*)(ws + off); off += 6291456;
    u16* wpb = (u16*)(ws + off); off += 2097152;
    u16* qf  = (u16*)(ws + off); off += 16777216;
    u16* kf  = (u16*)(ws + off); off += 16777216;
    u16* vt  = (u16*)(ws + off); off += 16777216;
    u16* yb  = (u16*)(ws + off); off += 16777216;

    split16_kernel<<<8192, 256, 0, stream>>>(x, xh, xl, 8192 * 1024 / 4);
    cvt16_kernel<<<3072, 256, 0, stream>>>(Wa, wf, 3072 * 1024 / 4);
    cvt16_kernel<<<1024, 256, 0, stream>>>(Wp, wpb, 1024 * 1024 / 4);
    qkv_gemm2<<<1536, 256, 0, stream>>>(xh, xl, wf, qkv);
    rotary_kernel<<<32768, 256, 0, stream>>>(qkv, qf, kf, vt);
    attn2_kernel<<<1024, 256, 0, stream>>>(qf, kf, vt, yb);
    proj_gemm2<<<512, 256, 0, stream>>>(yb, wpb, out);
}

// Round 5
// 373.412 us; speedup vs baseline: 1.2418x; 1.2418x over previous
//
#include <hip/hip_runtime.h>

typedef __attribute__((ext_vector_type(8))) short v8s;
typedef __attribute__((ext_vector_type(8))) _Float16 f16x8;
typedef __attribute__((ext_vector_type(4))) _Float16 f16x4;
typedef __attribute__((ext_vector_type(4))) float f32x4;
typedef unsigned short u16;

#define MFMAH(a,b,c) __builtin_amdgcn_mfma_f32_16x16x32_f16((a),(b),(c),0,0,0)
#define L2E 1.4426950408889634f

__device__ __forceinline__ u16 f2h(float f) {
    _Float16 h = (_Float16)f;
    return __builtin_bit_cast(u16, h);
}

__device__ __forceinline__ void gload16(const u16* g, u16* l) {
    __builtin_amdgcn_global_load_lds((const __attribute__((address_space(1))) void*)g,
                                     (__attribute__((address_space(3))) void*)l, 16, 0, 0);
}

// Stage a 128x64 f16 tile (row stride 1024 elems) into LDS.
// LDS dest is linear (gload_lds writes base+lane*16); the XOR slot-swizzle
// (slot' = slot ^ (row&7)) is applied by permuting the per-lane GLOBAL source
// (G21: both-sides-or-neither). Wave w stages rows [32w, 32w+32).
__device__ __forceinline__ void stage_tile(const u16* __restrict__ base, u16* lds, int w, int lane) {
    const int rsub = lane >> 3;
    const int s_org = (lane & 7) ^ rsub;
#pragma unroll
    for (int i = 0; i < 4; ++i) {
        const u16* src = base + (size_t)(32 * w + 8 * i + rsub) * 1024 + 8 * s_org;
        gload16(src, lds + (32 * w + 8 * i) * 64);
    }
}

// Stage a 64x64 f16 tile (arbitrary row stride) into LDS with the same
// XOR slot-swizzle via pre-swizzled global source. Wave w stages rows [16w,16w+16).
__device__ __forceinline__ void stage64(const u16* __restrict__ base, size_t rstride,
                                        u16* lds, int w, int lane) {
    const int rsub = lane >> 3;
    const int s_org = (lane & 7) ^ rsub;
#pragma unroll
    for (int i = 0; i < 2; ++i) {
        const u16* src = base + (size_t)(16 * w + 8 * i + rsub) * rstride + 8 * s_org;
        gload16(src, lds + (16 * w + 8 * i) * 64);
    }
}

// ---------------- elementwise converts ----------------
__global__ __launch_bounds__(256) void split16_kernel(const float* __restrict__ in,
                                                      u16* __restrict__ hi, u16* __restrict__ lo, int n4) {
    int i = blockIdx.x * 256 + threadIdx.x;
    if (i >= n4) return;
    f32x4 v = ((const f32x4*)in)[i];
    f16x4 h, l;
#pragma unroll
    for (int j = 0; j < 4; ++j) {
        _Float16 hh = (_Float16)v[j];
        h[j] = hh;
        l[j] = (_Float16)(v[j] - (float)hh);
    }
    ((f16x4*)hi)[i] = h;
    ((f16x4*)lo)[i] = l;
}

__global__ __launch_bounds__(256) void cvt16_kernel(const float* __restrict__ in, u16* __restrict__ out, int n4) {
    int i = blockIdx.x * 256 + threadIdx.x;
    if (i >= n4) return;
    f32x4 v = ((const f32x4*)in)[i];
    f16x4 h;
#pragma unroll
    for (int j = 0; j < 4; ++j) h[j] = (_Float16)v[j];
    ((f16x4*)out)[i] = h;
}

// ---------------- qkv GEMM: (8192x1024) x (3072x1024)^T ----------------
// q,k columns: acc = xh*w + xl*w (exact-x * fp16-w). v columns: xh*w only.
__global__ __launch_bounds__(256) void qkv_gemm2(const u16* __restrict__ xh, const u16* __restrict__ xl,
                                                 const u16* __restrict__ wf, float* __restrict__ qkv) {
    __shared__ u16 sAh[8192], sAl[8192], sB[8192];
    const int bid = blockIdx.x;
    const int swz = (bid & 7) * 192 + (bid >> 3);   // 1536 = 8*192, bijective XCD swizzle
    const int mb = swz / 24, nb = swz % 24;
    const int m0 = mb * 128, n0 = nb * 128;
    const bool lo = (nb < 16);                      // q,k thirds get the lo term
    const int tid = threadIdx.x, lane = tid & 63, w = tid >> 6;
    const int wr = w >> 1, wc = w & 1;
    const int fr = lane & 15, fq = lane >> 4;
    const u16* pa = xh + (size_t)m0 * 1024;
    const u16* pal = xl + (size_t)m0 * 1024;
    const u16* pb = wf + (size_t)n0 * 1024;
    f32x4 acc[4][4] = {};
    for (int k0 = 0; k0 < 1024; k0 += 64) {
        stage_tile(pa + k0, sAh, w, lane);
        stage_tile(pb + k0, sB, w, lane);
        if (lo) stage_tile(pal + k0, sAl, w, lane);
        __syncthreads();
#pragma unroll
        for (int kk = 0; kk < 2; ++kk) {
            f16x8 ah[4], al[4], bb[4];
#pragma unroll
            for (int m = 0; m < 4; ++m) {
                int row = wr * 64 + m * 16 + fr;
                int off = row * 64 + ((((kk * 4 + fq)) ^ (fr & 7)) << 3);
                ah[m] = *(const f16x8*)&sAh[off];
                if (lo) al[m] = *(const f16x8*)&sAl[off];
            }
#pragma unroll
            for (int n = 0; n < 4; ++n) {
                int row = wc * 64 + n * 16 + fr;
                bb[n] = *(const f16x8*)&sB[row * 64 + ((((kk * 4 + fq)) ^ (fr & 7)) << 3)];
            }
#pragma unroll
            for (int n = 0; n < 4; ++n)
#pragma unroll
                for (int m = 0; m < 4; ++m) {
                    acc[m][n] = MFMAH(ah[m], bb[n], acc[m][n]);
                    if (lo) acc[m][n] = MFMAH(al[m], bb[n], acc[m][n]);
                }
        }
        __syncthreads();
    }
#pragma unroll
    for (int m = 0; m < 4; ++m) {
        int rowb = m0 + wr * 64 + m * 16 + fq * 4;
#pragma unroll
        for (int n = 0; n < 4; ++n) {
            int col = n0 + wc * 64 + n * 16 + fr;
#pragma unroll
            for (int r = 0; r < 4; ++r)
                qkv[(size_t)(rowb + r) * 3072 + col] = acc[m][n][r];
        }
    }
}

// ---------------- rotary (cos/sin of q), fp16 outputs, transpose v ----------------
__global__ __launch_bounds__(256) void rotary_kernel(const float* __restrict__ qkv,
                                                     u16* __restrict__ qf, u16* __restrict__ kf,
                                                     u16* __restrict__ vt) {
    int rid = blockIdx.x * 4 + (threadIdx.x >> 6);
    int lane = threadIdx.x & 63;
    int b = rid >> 14, h = (rid >> 10) & 15, t = rid & 1023;
    const float* base = qkv + (size_t)(b * 1024 + t) * 3072 + h * 64 + lane;
    float q = base[0], k = base[1024], v = base[2048];
    float s, c;
    sincosf(q, &s, &c);
    int src = (lane < 32) ? (2 * lane + 1) : (2 * lane - 64);
    float qp = __shfl(q, src);
    float kp = __shfl(k, src);
    float rq = (lane < 32) ? -qp : qp;
    float rk = (lane < 32) ? -kp : kp;
    float q2 = q * c + rq * s;
    float k2 = k * c + rk * s;
    size_t oi = (size_t)((b * 16 + h) * 1024 + t) * 64 + lane;
    qf[oi] = f2h(q2);
    kf[oi] = f2h(k2);
    vt[(size_t)((b * 16 + h) * 64 + lane) * 1024 + t] = f2h(v);
}

// ---------------- flash attention, causal, scale=1.0, fp16 ----------------
// One K/V-tile step: QK^T -> online softmax update -> P -> PV.
__device__ __forceinline__ void attn_step(const f16x8* qfr, f32x4* accy, float* m_r, float* l_r,
                                          const u16* sK, const u16* sV, u16* sP,
                                          bool diag, int w, int lane) {
    const int fr = lane & 15, fq = lane >> 4;
    f32x4 s[4] = {};
#pragma unroll
    for (int n = 0; n < 4; ++n) {
        int krow = n * 16 + fr;
#pragma unroll
        for (int kk = 0; kk < 2; ++kk) {
            int sl = kk * 4 + fq;
            f16x8 kb = *(const f16x8*)&sK[krow * 64 + ((sl ^ (krow & 7)) << 3)];
            s[n] = MFMAH(qfr[kk], kb, s[n]);
        }
    }
    if (diag) {
        int rowb = w * 16 + fq * 4;
#pragma unroll
        for (int n = 0; n < 4; ++n)
#pragma unroll
            for (int r = 0; r < 4; ++r)
                if (n * 16 + fr > rowb + r) s[n][r] = -1e30f;
    }
    float alpha[4];
#pragma unroll
    for (int r = 0; r < 4; ++r) {
        float mx = fmaxf(fmaxf(s[0][r], s[1][r]), fmaxf(s[2][r], s[3][r]));
        mx = fmaxf(mx, __shfl_xor(mx, 1));
        mx = fmaxf(mx, __shfl_xor(mx, 2));
        mx = fmaxf(mx, __shfl_xor(mx, 4));
        mx = fmaxf(mx, __shfl_xor(mx, 8));
        float mn = fmaxf(m_r[r], mx);
        alpha[r] = exp2f((m_r[r] - mn) * L2E);
        m_r[r] = mn;
        float rs = 0.f;
#pragma unroll
        for (int n = 0; n < 4; ++n) {
            float p = exp2f((s[n][r] - mn) * L2E);
            s[n][r] = p;
            rs += p;
        }
        rs += __shfl_xor(rs, 1);
        rs += __shfl_xor(rs, 2);
        rs += __shfl_xor(rs, 4);
        rs += __shfl_xor(rs, 8);
        l_r[r] = l_r[r] * alpha[r] + rs;
    }
#pragma unroll
    for (int dn = 0; dn < 4; ++dn)
#pragma unroll
        for (int r = 0; r < 4; ++r) accy[dn][r] *= alpha[r];
    {
        int rowb = w * 16 + fq * 4;
#pragma unroll
        for (int n = 0; n < 4; ++n) {
            int key = n * 16 + fr;
            int s8 = key >> 3, kr = key & 7;
#pragma unroll
            for (int r = 0; r < 4; ++r) {
                int row = rowb + r;
                sP[row * 64 + (((s8 ^ (row & 7)) << 3) | kr)] = f2h(s[n][r]);
            }
        }
    }
    // P rows written & read by the same wave only: no barrier needed.
    f16x8 pa[2];
    {
        int prow = w * 16 + fr;
#pragma unroll
        for (int kk = 0; kk < 2; ++kk) {
            int sl = kk * 4 + fq;
            pa[kk] = *(const f16x8*)&sP[prow * 64 + ((sl ^ (prow & 7)) << 3)];
        }
    }
#pragma unroll
    for (int dn = 0; dn < 4; ++dn) {
        int vrow = dn * 16 + fr;
#pragma unroll
        for (int kk = 0; kk < 2; ++kk) {
            int sl = kk * 4 + fq;
            f16x8 vb = *(const f16x8*)&sV[vrow * 64 + ((sl ^ (vrow & 7)) << 3)];
            accy[dn] = MFMAH(pa[kk], vb, accy[dn]);
        }
    }
}

// Single q-tile per block (round-3 structure: 60 VGPR, no spills), with:
//  - 24 KB LDS (Q staged through sK in prologue; sP scratch) -> 6 blocks/CU
//  - XCD-aware mapping: all 16 q-tiles of a head on one XCD (bid%8 round-robin
//    assumption) so the head's 256 KB K/V stays in that XCD's 4 MB L2.
__global__ __launch_bounds__(256) void attn3_kernel(const u16* __restrict__ qf, const u16* __restrict__ kf,
                                                    const u16* __restrict__ vt, u16* __restrict__ yb) {
    __shared__ u16 sK[4096], sV[4096], sP[4096];
    const int r8 = blockIdx.x & 7, j = blockIdx.x >> 3;
    const int bh = r8 * 16 + (j >> 4);
    const int qt = j & 15;
    const int b = bh >> 4, h = bh & 15;
    const int tid = threadIdx.x, lane = tid & 63, w = tid >> 6;
    const int fr = lane & 15, fq = lane >> 4;

    // Prologue: stage Q tile into sK, read frags to registers.
    stage64(qf + (size_t)bh * 65536 + qt * 4096, 64, sK, w, lane);
    __syncthreads();
    f16x8 qfr[2];
    {
        int row = w * 16 + fr;
#pragma unroll
        for (int kk = 0; kk < 2; ++kk) {
            int sl = kk * 4 + fq;
            qfr[kk] = *(const f16x8*)&sK[row * 64 + ((sl ^ (row & 7)) << 3)];
        }
    }
    f32x4 accy[4] = {};
    float m_r[4], l_r[4];
#pragma unroll
    for (int r = 0; r < 4; ++r) { m_r[r] = -1e30f; l_r[r] = 0.f; }
    const u16* kbase = kf + (size_t)bh * 65536;
    const u16* vbase = vt + (size_t)bh * 65536;

    for (int kt = 0; kt <= qt; ++kt) {
        __syncthreads();                      // prior reads of sK/sV done (incl. prologue q-frags)
        stage64(kbase + kt * 4096, 64, sK, w, lane);
        stage64(vbase + kt * 64, 1024, sV, w, lane);
        __syncthreads();                      // staging visible (barrier drains vmcnt)
        attn_step(qfr, accy, m_r, l_r, sK, sV, sP, kt == qt, w, lane);
    }
    {
        int rowbase = qt * 64 + w * 16 + fq * 4;
        int colb = h * 64 + fr;
#pragma unroll
        for (int r = 0; r < 4; ++r) {
            float inv = 1.0f / l_r[r];
#pragma unroll
            for (int dn = 0; dn < 4; ++dn)
                yb[(size_t)(b * 1024 + rowbase + r) * 1024 + colb + dn * 16] = f2h(accy[dn][r] * inv);
        }
    }
}

// ---------------- out projection: (8192x1024) x (1024x1024)^T, fp16 ----------------
__global__ __launch_bounds__(256) void proj_gemm2(const u16* __restrict__ yb, const u16* __restrict__ wpb,
                                                  float* __restrict__ out) {
    __shared__ u16 sA[8192], sB[8192];
    const int bid = blockIdx.x;
    const int swz = (bid & 7) * 64 + (bid >> 3);    // 512 = 8*64
    const int mb = swz >> 3, nb = swz & 7;
    const int m0 = mb * 128, n0 = nb * 128;
    const int tid = threadIdx.x, lane = tid & 63, w = tid >> 6;
    const int wr = w >> 1, wc = w & 1;
    const int fr = lane & 15, fq = lane >> 4;
    const u16* pa = yb + (size_t)m0 * 1024;
    const u16* pb = wpb + (size_t)n0 * 1024;
    f32x4 acc[4][4] = {};
    for (int k0 = 0; k0 < 1024; k0 += 64) {
        stage_tile(pa + k0, sA, w, lane);
        stage_tile(pb + k0, sB, w, lane);
        __syncthreads();
#pragma unroll
        for (int kk = 0; kk < 2; ++kk) {
            f16x8 af[4], bb[4];
#pragma unroll
            for (int m = 0; m < 4; ++m) {
                int row = wr * 64 + m * 16 + fr;
                af[m] = *(const f16x8*)&sA[row * 64 + ((((kk * 4 + fq)) ^ (fr & 7)) << 3)];
            }
#pragma unroll
            for (int n = 0; n < 4; ++n) {
                int row = wc * 64 + n * 16 + fr;
                bb[n] = *(const f16x8*)&sB[row * 64 + ((((kk * 4 + fq)) ^ (fr & 7)) << 3)];
            }
#pragma unroll
            for (int n = 0; n < 4; ++n)
#pragma unroll
                for (int m = 0; m < 4; ++m) acc[m][n] = MFMAH(af[m], bb[n], acc[m][n]);
        }
        __syncthreads();
    }
#pragma unroll
    for (int m = 0; m < 4; ++m) {
        int rowb = m0 + wr * 64 + m * 16 + fq * 4;
#pragma unroll
        for (int n = 0; n < 4; ++n) {
            int col = n0 + wc * 64 + n * 16 + fr;
#pragma unroll
            for (int r = 0; r < 4; ++r) out[(size_t)(rowb + r) * 1024 + col] = acc[m][n][r];
        }
    }
}

extern "C" void kernel_launch(void* const* d_in, const int* in_sizes, int n_in,
                              void* d_out, int out_size, void* d_ws, size_t ws_size,
                              hipStream_t stream) {
    const float* x  = (const float*)d_in[0];
    const float* Wa = (const float*)d_in[1];
    const float* Wp = (const float*)d_in[2];
    float* out = (float*)d_out;
    char* ws = (char*)d_ws;
    size_t off = 0;
    float* qkv = (float*)(ws + off); off += (size_t)8192 * 3072 * 4;   // 96 MB
    u16* xh  = (u16*)(ws + off); off += 16777216;
    u16* xl  = (u16*)(ws + off); off += 16777216;
    u16* wf  = (u16*)(ws + off); off += 6291456;
    u16* wpb = (u16*)(ws + off); off += 2097152;
    u16* qf  = (u16*)(ws + off); off += 16777216;
    u16* kf  = (u16*)(ws + off); off += 16777216;
    u16* vt  = (u16*)(ws + off); off += 16777216;
    u16* yb  = (u16*)(ws + off); off += 16777216;

    split16_kernel<<<8192, 256, 0, stream>>>(x, xh, xl, 8192 * 1024 / 4);
    cvt16_kernel<<<3072, 256, 0, stream>>>(Wa, wf, 3072 * 1024 / 4);
    cvt16_kernel<<<1024, 256, 0, stream>>>(Wp, wpb, 1024 * 1024 / 4);
    qkv_gemm2<<<1536, 256, 0, stream>>>(xh, xl, wf, qkv);
    rotary_kernel<<<32768, 256, 0, stream>>>(qkv, qf, kf, vt);
    attn3_kernel<<<2048, 256, 0, stream>>>(qf, kf, vt, yb);
    proj_gemm2<<<512, 256, 0, stream>>>(yb, wpb, out);
}

// Round 8
// 358.469 us; speedup vs baseline: 1.2936x; 1.0417x over previous
//
#include <hip/hip_runtime.h>

typedef __attribute__((ext_vector_type(8))) short v8s;
typedef __attribute__((ext_vector_type(8))) _Float16 f16x8;
typedef __attribute__((ext_vector_type(4))) _Float16 f16x4;
typedef __attribute__((ext_vector_type(4))) float f32x4;
typedef unsigned short u16;

#define MFMAH(a,b,c) __builtin_amdgcn_mfma_f32_16x16x32_f16((a),(b),(c),0,0,0)
#define L2E 1.4426950408889634f

__device__ __forceinline__ u16 f2h(float f) {
    _Float16 h = (_Float16)f;
    return __builtin_bit_cast(u16, h);
}

__device__ __forceinline__ void gload16(const u16* g, u16* l) {
    __builtin_amdgcn_global_load_lds((const __attribute__((address_space(1))) void*)g,
                                     (__attribute__((address_space(3))) void*)l, 16, 0, 0);
}

// Stage a 128x64 f16 tile (row stride 1024 elems) into LDS.
// LDS dest is linear (gload_lds writes base+lane*16); the XOR slot-swizzle
// (slot' = slot ^ (row&7)) is applied by permuting the per-lane GLOBAL source
// (G21: both-sides-or-neither). Wave w stages rows [32w, 32w+32).
__device__ __forceinline__ void stage_tile(const u16* __restrict__ base, u16* lds, int w, int lane) {
    const int rsub = lane >> 3;
    const int s_org = (lane & 7) ^ rsub;
#pragma unroll
    for (int i = 0; i < 4; ++i) {
        const u16* src = base + (size_t)(32 * w + 8 * i + rsub) * 1024 + 8 * s_org;
        gload16(src, lds + (32 * w + 8 * i) * 64);
    }
}

// Stage a 64x64 f16 tile (arbitrary row stride) into LDS with the same
// XOR slot-swizzle via pre-swizzled global source. Wave w stages rows [16w,16w+16).
__device__ __forceinline__ void stage64(const u16* __restrict__ base, size_t rstride,
                                        u16* lds, int w, int lane) {
    const int rsub = lane >> 3;
    const int s_org = (lane & 7) ^ rsub;
#pragma unroll
    for (int i = 0; i < 2; ++i) {
        const u16* src = base + (size_t)(16 * w + 8 * i + rsub) * rstride + 8 * s_org;
        gload16(src, lds + (16 * w + 8 * i) * 64);
    }
}

// ---------------- elementwise converts ----------------
__global__ __launch_bounds__(256) void split16_kernel(const float* __restrict__ in,
                                                      u16* __restrict__ hi, u16* __restrict__ lo, int n4) {
    int i = blockIdx.x * 256 + threadIdx.x;
    if (i >= n4) return;
    f32x4 v = ((const f32x4*)in)[i];
    f16x4 h, l;
#pragma unroll
    for (int j = 0; j < 4; ++j) {
        _Float16 hh = (_Float16)v[j];
        h[j] = hh;
        l[j] = (_Float16)(v[j] - (float)hh);
    }
    ((f16x4*)hi)[i] = h;
    ((f16x4*)lo)[i] = l;
}

__global__ __launch_bounds__(256) void cvt16_kernel(const float* __restrict__ in, u16* __restrict__ out, int n4) {
    int i = blockIdx.x * 256 + threadIdx.x;
    if (i >= n4) return;
    f32x4 v = ((const f32x4*)in)[i];
    f16x4 h;
#pragma unroll
    for (int j = 0; j < 4; ++j) h[j] = (_Float16)v[j];
    ((f16x4*)out)[i] = h;
}

// ---------------- qkv GEMM: (8192x1024) x (3072x1024)^T ----------------
// q,k columns: acc = xh*w + xl*w (exact-x * fp16-w). v columns: xh*w only.
__global__ __launch_bounds__(256) void qkv_gemm2(const u16* __restrict__ xh, const u16* __restrict__ xl,
                                                 const u16* __restrict__ wf, float* __restrict__ qkv) {
    __shared__ u16 sAh[8192], sAl[8192], sB[8192];
    const int bid = blockIdx.x;
    const int swz = (bid & 7) * 192 + (bid >> 3);   // 1536 = 8*192, bijective XCD swizzle
    const int mb = swz / 24, nb = swz % 24;
    const int m0 = mb * 128, n0 = nb * 128;
    const bool lo = (nb < 16);                      // q,k thirds get the lo term
    const int tid = threadIdx.x, lane = tid & 63, w = tid >> 6;
    const int wr = w >> 1, wc = w & 1;
    const int fr = lane & 15, fq = lane >> 4;
    const u16* pa = xh + (size_t)m0 * 1024;
    const u16* pal = xl + (size_t)m0 * 1024;
    const u16* pb = wf + (size_t)n0 * 1024;
    f32x4 acc[4][4] = {};
    for (int k0 = 0; k0 < 1024; k0 += 64) {
        stage_tile(pa + k0, sAh, w, lane);
        stage_tile(pb + k0, sB, w, lane);
        if (lo) stage_tile(pal + k0, sAl, w, lane);
        __syncthreads();
#pragma unroll
        for (int kk = 0; kk < 2; ++kk) {
            f16x8 ah[4], al[4], bb[4];
#pragma unroll
            for (int m = 0; m < 4; ++m) {
                int row = wr * 64 + m * 16 + fr;
                int off = row * 64 + ((((kk * 4 + fq)) ^ (fr & 7)) << 3);
                ah[m] = *(const f16x8*)&sAh[off];
                if (lo) al[m] = *(const f16x8*)&sAl[off];
            }
#pragma unroll
            for (int n = 0; n < 4; ++n) {
                int row = wc * 64 + n * 16 + fr;
                bb[n] = *(const f16x8*)&sB[row * 64 + ((((kk * 4 + fq)) ^ (fr & 7)) << 3)];
            }
#pragma unroll
            for (int n = 0; n < 4; ++n)
#pragma unroll
                for (int m = 0; m < 4; ++m) {
                    acc[m][n] = MFMAH(ah[m], bb[n], acc[m][n]);
                    if (lo) acc[m][n] = MFMAH(al[m], bb[n], acc[m][n]);
                }
        }
        __syncthreads();
    }
#pragma unroll
    for (int m = 0; m < 4; ++m) {
        int rowb = m0 + wr * 64 + m * 16 + fq * 4;
#pragma unroll
        for (int n = 0; n < 4; ++n) {
            int col = n0 + wc * 64 + n * 16 + fr;
#pragma unroll
            for (int r = 0; r < 4; ++r)
                qkv[(size_t)(rowb + r) * 3072 + col] = acc[m][n][r];
        }
    }
}

// ---------------- rotary (cos/sin of q), fp16 outputs, transpose v ----------------
__global__ __launch_bounds__(256) void rotary_kernel(const float* __restrict__ qkv,
                                                     u16* __restrict__ qf, u16* __restrict__ kf,
                                                     u16* __restrict__ vt) {
    int rid = blockIdx.x * 4 + (threadIdx.x >> 6);
    int lane = threadIdx.x & 63;
    int b = rid >> 14, h = (rid >> 10) & 15, t = rid & 1023;
    const float* base = qkv + (size_t)(b * 1024 + t) * 3072 + h * 64 + lane;
    float q = base[0], k = base[1024], v = base[2048];
    float s, c;
    sincosf(q, &s, &c);
    int src = (lane < 32) ? (2 * lane + 1) : (2 * lane - 64);
    float qp = __shfl(q, src);
    float kp = __shfl(k, src);
    float rq = (lane < 32) ? -qp : qp;
    float rk = (lane < 32) ? -kp : kp;
    float q2 = q * c + rq * s;
    float k2 = k * c + rk * s;
    size_t oi = (size_t)((b * 16 + h) * 1024 + t) * 64 + lane;
    qf[oi] = f2h(q2);
    kf[oi] = f2h(k2);
    vt[(size_t)((b * 16 + h) * 64 + lane) * 1024 + t] = f2h(v);
}

// ---------------- flash attention, causal, scale=1.0, fp16 ----------------
// One K/V-tile step: QK^T -> online softmax update -> P -> PV.
__device__ __forceinline__ void attn_step(const f16x8* qfr, f32x4* accy, float* m_r, float* l_r,
                                          const u16* sK, const u16* sV, u16* sP,
                                          bool diag, int w, int lane) {
    const int fr = lane & 15, fq = lane >> 4;
    f32x4 s[4] = {};
    __builtin_amdgcn_s_setprio(1);
#pragma unroll
    for (int n = 0; n < 4; ++n) {
        int krow = n * 16 + fr;
#pragma unroll
        for (int kk = 0; kk < 2; ++kk) {
            int sl = kk * 4 + fq;
            f16x8 kb = *(const f16x8*)&sK[krow * 64 + ((sl ^ (krow & 7)) << 3)];
            s[n] = MFMAH(qfr[kk], kb, s[n]);
        }
    }
    __builtin_amdgcn_s_setprio(0);
    if (diag) {
        int rowb = w * 16 + fq * 4;
#pragma unroll
        for (int n = 0; n < 4; ++n)
#pragma unroll
            for (int r = 0; r < 4; ++r)
                if (n * 16 + fr > rowb + r) s[n][r] = -1e30f;
    }
    float alpha[4];
#pragma unroll
    for (int r = 0; r < 4; ++r) {
        float mx = fmaxf(fmaxf(s[0][r], s[1][r]), fmaxf(s[2][r], s[3][r]));
        mx = fmaxf(mx, __shfl_xor(mx, 1));
        mx = fmaxf(mx, __shfl_xor(mx, 2));
        mx = fmaxf(mx, __shfl_xor(mx, 4));
        mx = fmaxf(mx, __shfl_xor(mx, 8));
        float mn = fmaxf(m_r[r], mx);
        alpha[r] = exp2f((m_r[r] - mn) * L2E);
        m_r[r] = mn;
        float rs = 0.f;
#pragma unroll
        for (int n = 0; n < 4; ++n) {
            float p = exp2f((s[n][r] - mn) * L2E);
            s[n][r] = p;
            rs += p;
        }
        rs += __shfl_xor(rs, 1);
        rs += __shfl_xor(rs, 2);
        rs += __shfl_xor(rs, 4);
        rs += __shfl_xor(rs, 8);
        l_r[r] = l_r[r] * alpha[r] + rs;
    }
#pragma unroll
    for (int dn = 0; dn < 4; ++dn)
#pragma unroll
        for (int r = 0; r < 4; ++r) accy[dn][r] *= alpha[r];
    {
        int rowb = w * 16 + fq * 4;
#pragma unroll
        for (int n = 0; n < 4; ++n) {
            int key = n * 16 + fr;
            int s8 = key >> 3, kr = key & 7;
#pragma unroll
            for (int r = 0; r < 4; ++r) {
                int row = rowb + r;
                sP[row * 64 + (((s8 ^ (row & 7)) << 3) | kr)] = f2h(s[n][r]);
            }
        }
    }
    // P rows written & read by the same wave only (rows [16w,16w+16)): no barrier.
    f16x8 pa[2];
    {
        int prow = w * 16 + fr;
#pragma unroll
        for (int kk = 0; kk < 2; ++kk) {
            int sl = kk * 4 + fq;
            pa[kk] = *(const f16x8*)&sP[prow * 64 + ((sl ^ (prow & 7)) << 3)];
        }
    }
    __builtin_amdgcn_s_setprio(1);
#pragma unroll
    for (int dn = 0; dn < 4; ++dn) {
        int vrow = dn * 16 + fr;
#pragma unroll
        for (int kk = 0; kk < 2; ++kk) {
            int sl = kk * 4 + fq;
            f16x8 vb = *(const f16x8*)&sV[vrow * 64 + ((sl ^ (vrow & 7)) << 3)];
            accy[dn] = MFMAH(pa[kk], vb, accy[dn]);
        }
    }
    __builtin_amdgcn_s_setprio(0);
}

// Single q-tile per block; double-buffered K/V with ONE barrier per step
// (T3-minimum pattern): issue stage(kt+1) -> compute(kt) -> barrier.
// The implicit vmcnt-drain at the barrier lands after a full compute phase,
// so the K/V load latency is hidden. LDS 40KB -> 4 blocks/CU.
// XCD-aware mapping: all 16 q-tiles of a head on one XCD (bid%8 round-robin)
// so the head's 256 KB K/V stays in that XCD's 4 MB L2.
__global__ __launch_bounds__(256) void attn4_kernel(const u16* __restrict__ qf, const u16* __restrict__ kf,
                                                    const u16* __restrict__ vt, u16* __restrict__ yb) {
    __shared__ u16 sK[2][4096], sV[2][4096], sP[4096];
    const int r8 = blockIdx.x & 7, j = blockIdx.x >> 3;
    const int bh = r8 * 16 + (j >> 4);
    const int qt = j & 15;
    const int b = bh >> 4, h = bh & 15;
    const int tid = threadIdx.x, lane = tid & 63, w = tid >> 6;
    const int fr = lane & 15, fq = lane >> 4;
    const u16* kbase = kf + (size_t)bh * 65536;
    const u16* vbase = vt + (size_t)bh * 65536;

    // Prologue: Q through sP (wave-private rows), K/V tile 0 into buffer 0.
    stage64(qf + (size_t)bh * 65536 + qt * 4096, 64, sP, w, lane);
    stage64(kbase, 64, sK[0], w, lane);
    stage64(vbase, 1024, sV[0], w, lane);
    __syncthreads();   // drains DMA (compiler emits vmcnt(0) before s_barrier)
    f16x8 qfr[2];
    {
        int row = w * 16 + fr;
#pragma unroll
        for (int kk = 0; kk < 2; ++kk) {
            int sl = kk * 4 + fq;
            qfr[kk] = *(const f16x8*)&sP[row * 64 + ((sl ^ (row & 7)) << 3)];
        }
    }
    f32x4 accy[4] = {};
    float m_r[4], l_r[4];
#pragma unroll
    for (int r = 0; r < 4; ++r) { m_r[r] = -1e30f; l_r[r] = 0.f; }

    int cur = 0;
    for (int kt = 0; kt <= qt; ++kt) {
        if (kt < qt) {   // issue next tile's DMA before computing current
            stage64(kbase + (kt + 1) * 4096, 64, sK[cur ^ 1], w, lane);
            stage64(vbase + (kt + 1) * 64, 1024, sV[cur ^ 1], w, lane);
        }
        attn_step(qfr, accy, m_r, l_r, sK[cur], sV[cur], sP, kt == qt, w, lane);
        __syncthreads();  // drains this wave's DMA + orders buf[cur^1] reuse
        cur ^= 1;
    }
    {
        int rowbase = qt * 64 + w * 16 + fq * 4;
        int colb = h * 64 + fr;
#pragma unroll
        for (int r = 0; r < 4; ++r) {
            float inv = 1.0f / l_r[r];
#pragma unroll
            for (int dn = 0; dn < 4; ++dn)
                yb[(size_t)(b * 1024 + rowbase + r) * 1024 + colb + dn * 16] = f2h(accy[dn][r] * inv);
        }
    }
}

// ---------------- out projection: (8192x1024) x (1024x1024)^T, fp16 ----------------
__global__ __launch_bounds__(256) void proj_gemm2(const u16* __restrict__ yb, const u16* __restrict__ wpb,
                                                  float* __restrict__ out) {
    __shared__ u16 sA[8192], sB[8192];
    const int bid = blockIdx.x;
    const int swz = (bid & 7) * 64 + (bid >> 3);    // 512 = 8*64
    const int mb = swz >> 3, nb = swz & 7;
    const int m0 = mb * 128, n0 = nb * 128;
    const int tid = threadIdx.x, lane = tid & 63, w = tid >> 6;
    const int wr = w >> 1, wc = w & 1;
    const int fr = lane & 15, fq = lane >> 4;
    const u16* pa = yb + (size_t)m0 * 1024;
    const u16* pb = wpb + (size_t)n0 * 1024;
    f32x4 acc[4][4] = {};
    for (int k0 = 0; k0 < 1024; k0 += 64) {
        stage_tile(pa + k0, sA, w, lane);
        stage_tile(pb + k0, sB, w, lane);
        __syncthreads();
#pragma unroll
        for (int kk = 0; kk < 2; ++kk) {
            f16x8 af[4], bb[4];
#pragma unroll
            for (int m = 0; m < 4; ++m) {
                int row = wr * 64 + m * 16 + fr;
                af[m] = *(const f16x8*)&sA[row * 64 + ((((kk * 4 + fq)) ^ (fr & 7)) << 3)];
            }
#pragma unroll
            for (int n = 0; n < 4; ++n) {
                int row = wc * 64 + n * 16 + fr;
                bb[n] = *(const f16x8*)&sB[row * 64 + ((((kk * 4 + fq)) ^ (fr & 7)) << 3)];
            }
#pragma unroll
            for (int n = 0; n < 4; ++n)
#pragma unroll
                for (int m = 0; m < 4; ++m) acc[m][n] = MFMAH(af[m], bb[n], acc[m][n]);
        }
        __syncthreads();
    }
#pragma unroll
    for (int m = 0; m < 4; ++m) {
        int rowb = m0 + wr * 64 + m * 16 + fq * 4;
#pragma unroll
        for (int n = 0; n < 4; ++n) {
            int col = n0 + wc * 64 + n * 16 + fr;
#pragma unroll
            for (int r = 0; r < 4; ++r) out[(size_t)(rowb + r) * 1024 + col] = acc[m][n][r];
        }
    }
}

extern "C" void kernel_launch(void* const* d_in, const int* in_sizes, int n_in,
                              void* d_out, int out_size, void* d_ws, size_t ws_size,
                              hipStream_t stream) {
    const float* x  = (const float*)d_in[0];
    const float* Wa = (const float*)d_in[1];
    const float* Wp = (const float*)d_in[2];
    float* out = (float*)d_out;
    char* ws = (char*)d_ws;
    size_t off = 0;
    float* qkv = (float*)(ws + off); off += (size_t)8192 * 3072 * 4;   // 96 MB
    u16* xh  = (u16*)(ws + off); off += 16777216;
    u16* xl  = (u16*)(ws + off); off += 16777216;
    u16* wf  = (u16*)(ws + off); off += 6291456;
    u16* wpb = (u16*)(ws + off); off += 2097152;
    u16* qf  = (u16*)(ws + off); off += 16777216;
    u16* kf  = (u16*)(ws + off); off += 16777216;
    u16* vt  = (u16*)(ws + off); off += 16777216;
    u16* yb  = (u16*)(ws + off); off += 16777216;

    split16_kernel<<<8192, 256, 0, stream>>>(x, xh, xl, 8192 * 1024 / 4);
    cvt16_kernel<<<3072, 256, 0, stream>>>(Wa, wf, 3072 * 1024 / 4);
    cvt16_kernel<<<1024, 256, 0, stream>>>(Wp, wpb, 1024 * 1024 / 4);
    qkv_gemm2<<<1536, 256, 0, stream>>>(xh, xl, wf, qkv);
    rotary_kernel<<<32768, 256, 0, stream>>>(qkv, qf, kf, vt);
    attn4_kernel<<<2048, 256, 0, stream>>>(qf, kf, vt, yb);
    proj_gemm2<<<512, 256, 0, stream>>>(yb, wpb, out);
}

// Round 9
// 350.272 us; speedup vs baseline: 1.3238x; 1.0234x over previous
//
#include <hip/hip_runtime.h>

typedef __attribute__((ext_vector_type(8))) short v8s;
typedef __attribute__((ext_vector_type(8))) _Float16 f16x8;
typedef __attribute__((ext_vector_type(4))) _Float16 f16x4;
typedef __attribute__((ext_vector_type(4))) float f32x4;
typedef unsigned short u16;

#define MFMAH(a,b,c) __builtin_amdgcn_mfma_f32_16x16x32_f16((a),(b),(c),0,0,0)
#define L2E 1.4426950408889634f

__device__ __forceinline__ u16 f2h(float f) {
    _Float16 h = (_Float16)f;
    return __builtin_bit_cast(u16, h);
}

__device__ __forceinline__ void gload16(const u16* g, u16* l) {
    __builtin_amdgcn_global_load_lds((const __attribute__((address_space(1))) void*)g,
                                     (__attribute__((address_space(3))) void*)l, 16, 0, 0);
}

// Stage a 128x64 f16 tile (row stride 1024 elems) into LDS.
// LDS dest is linear (gload_lds writes base+lane*16); the XOR slot-swizzle
// (slot' = slot ^ (row&7)) is applied by permuting the per-lane GLOBAL source
// (G21: both-sides-or-neither). Wave w stages rows [32w, 32w+32).
__device__ __forceinline__ void stage_tile(const u16* __restrict__ base, u16* lds, int w, int lane) {
    const int rsub = lane >> 3;
    const int s_org = (lane & 7) ^ rsub;
#pragma unroll
    for (int i = 0; i < 4; ++i) {
        const u16* src = base + (size_t)(32 * w + 8 * i + rsub) * 1024 + 8 * s_org;
        gload16(src, lds + (32 * w + 8 * i) * 64);
    }
}

// Stage a 64x64 f16 tile (arbitrary row stride) into LDS with the same
// XOR slot-swizzle via pre-swizzled global source. Wave w stages rows [16w,16w+16).
__device__ __forceinline__ void stage64(const u16* __restrict__ base, size_t rstride,
                                        u16* lds, int w, int lane) {
    const int rsub = lane >> 3;
    const int s_org = (lane & 7) ^ rsub;
#pragma unroll
    for (int i = 0; i < 2; ++i) {
        const u16* src = base + (size_t)(16 * w + 8 * i + rsub) * rstride + 8 * s_org;
        gload16(src, lds + (16 * w + 8 * i) * 64);
    }
}

// ---------------- elementwise converts ----------------
__global__ __launch_bounds__(256) void split16_kernel(const float* __restrict__ in,
                                                      u16* __restrict__ hi, u16* __restrict__ lo, int n4) {
    int i = blockIdx.x * 256 + threadIdx.x;
    if (i >= n4) return;
    f32x4 v = ((const f32x4*)in)[i];
    f16x4 h, l;
#pragma unroll
    for (int j = 0; j < 4; ++j) {
        _Float16 hh = (_Float16)v[j];
        h[j] = hh;
        l[j] = (_Float16)(v[j] - (float)hh);
    }
    ((f16x4*)hi)[i] = h;
    ((f16x4*)lo)[i] = l;
}

__global__ __launch_bounds__(256) void cvt16_kernel(const float* __restrict__ in, u16* __restrict__ out, int n4) {
    int i = blockIdx.x * 256 + threadIdx.x;
    if (i >= n4) return;
    f32x4 v = ((const f32x4*)in)[i];
    f16x4 h;
#pragma unroll
    for (int j = 0; j < 4; ++j) h[j] = (_Float16)v[j];
    ((f16x4*)out)[i] = h;
}

// ---------------- qkv GEMM: (8192x1024) x (3072x1024)^T ----------------
// q,k columns: acc = xh*w + xl*w (exact-x * fp16-w). v columns: xh*w only.
__global__ __launch_bounds__(256) void qkv_gemm2(const u16* __restrict__ xh, const u16* __restrict__ xl,
                                                 const u16* __restrict__ wf, float* __restrict__ qkv) {
    __shared__ u16 sAh[8192], sAl[8192], sB[8192];
    const int bid = blockIdx.x;
    const int swz = (bid & 7) * 192 + (bid >> 3);   // 1536 = 8*192, bijective XCD swizzle
    const int mb = swz / 24, nb = swz % 24;
    const int m0 = mb * 128, n0 = nb * 128;
    const bool lo = (nb < 16);                      // q,k thirds get the lo term
    const int tid = threadIdx.x, lane = tid & 63, w = tid >> 6;
    const int wr = w >> 1, wc = w & 1;
    const int fr = lane & 15, fq = lane >> 4;
    const u16* pa = xh + (size_t)m0 * 1024;
    const u16* pal = xl + (size_t)m0 * 1024;
    const u16* pb = wf + (size_t)n0 * 1024;
    f32x4 acc[4][4] = {};
    for (int k0 = 0; k0 < 1024; k0 += 64) {
        stage_tile(pa + k0, sAh, w, lane);
        stage_tile(pb + k0, sB, w, lane);
        if (lo) stage_tile(pal + k0, sAl, w, lane);
        __syncthreads();
#pragma unroll
        for (int kk = 0; kk < 2; ++kk) {
            f16x8 ah[4], al[4], bb[4];
#pragma unroll
            for (int m = 0; m < 4; ++m) {
                int row = wr * 64 + m * 16 + fr;
                int off = row * 64 + ((((kk * 4 + fq)) ^ (fr & 7)) << 3);
                ah[m] = *(const f16x8*)&sAh[off];
                if (lo) al[m] = *(const f16x8*)&sAl[off];
            }
#pragma unroll
            for (int n = 0; n < 4; ++n) {
                int row = wc * 64 + n * 16 + fr;
                bb[n] = *(const f16x8*)&sB[row * 64 + ((((kk * 4 + fq)) ^ (fr & 7)) << 3)];
            }
#pragma unroll
            for (int n = 0; n < 4; ++n)
#pragma unroll
                for (int m = 0; m < 4; ++m) {
                    acc[m][n] = MFMAH(ah[m], bb[n], acc[m][n]);
                    if (lo) acc[m][n] = MFMAH(al[m], bb[n], acc[m][n]);
                }
        }
        __syncthreads();
    }
#pragma unroll
    for (int m = 0; m < 4; ++m) {
        int rowb = m0 + wr * 64 + m * 16 + fq * 4;
#pragma unroll
        for (int n = 0; n < 4; ++n) {
            int col = n0 + wc * 64 + n * 16 + fr;
#pragma unroll
            for (int r = 0; r < 4; ++r)
                qkv[(size_t)(rowb + r) * 3072 + col] = acc[m][n][r];
        }
    }
}

// ---------------- rotary (cos/sin of q), fp16 outputs, transpose v ----------------
__global__ __launch_bounds__(256) void rotary_kernel(const float* __restrict__ qkv,
                                                     u16* __restrict__ qf, u16* __restrict__ kf,
                                                     u16* __restrict__ vt) {
    int rid = blockIdx.x * 4 + (threadIdx.x >> 6);
    int lane = threadIdx.x & 63;
    int b = rid >> 14, h = (rid >> 10) & 15, t = rid & 1023;
    const float* base = qkv + (size_t)(b * 1024 + t) * 3072 + h * 64 + lane;
    float q = base[0], k = base[1024], v = base[2048];
    float s, c;
    sincosf(q, &s, &c);
    int src = (lane < 32) ? (2 * lane + 1) : (2 * lane - 64);
    float qp = __shfl(q, src);
    float kp = __shfl(k, src);
    float rq = (lane < 32) ? -qp : qp;
    float rk = (lane < 32) ? -kp : kp;
    float q2 = q * c + rq * s;
    float k2 = k * c + rk * s;
    size_t oi = (size_t)((b * 16 + h) * 1024 + t) * 64 + lane;
    qf[oi] = f2h(q2);
    kf[oi] = f2h(k2);
    vt[(size_t)((b * 16 + h) * 64 + lane) * 1024 + t] = f2h(v);
}

// ---------------- flash attention, causal, scale=1.0, fp16 ----------------
// One K/V-tile step: QK^T -> online softmax update -> P -> PV.
__device__ __forceinline__ void attn_step(const f16x8* qfr, f32x4* accy, float* m_r, float* l_r,
                                          const u16* sK, const u16* sV, u16* sP,
                                          bool diag, int w, int lane) {
    const int fr = lane & 15, fq = lane >> 4;
    f32x4 s[4] = {};
    __builtin_amdgcn_s_setprio(1);
#pragma unroll
    for (int n = 0; n < 4; ++n) {
        int krow = n * 16 + fr;
#pragma unroll
        for (int kk = 0; kk < 2; ++kk) {
            int sl = kk * 4 + fq;
            f16x8 kb = *(const f16x8*)&sK[krow * 64 + ((sl ^ (krow & 7)) << 3)];
            s[n] = MFMAH(qfr[kk], kb, s[n]);
        }
    }
    __builtin_amdgcn_s_setprio(0);
    if (diag) {
        int rowb = w * 16 + fq * 4;
#pragma unroll
        for (int n = 0; n < 4; ++n)
#pragma unroll
            for (int r = 0; r < 4; ++r)
                if (n * 16 + fr > rowb + r) s[n][r] = -1e30f;
    }
    float alpha[4];
#pragma unroll
    for (int r = 0; r < 4; ++r) {
        float mx = fmaxf(fmaxf(s[0][r], s[1][r]), fmaxf(s[2][r], s[3][r]));
        mx = fmaxf(mx, __shfl_xor(mx, 1));
        mx = fmaxf(mx, __shfl_xor(mx, 2));
        mx = fmaxf(mx, __shfl_xor(mx, 4));
        mx = fmaxf(mx, __shfl_xor(mx, 8));
        float mn = fmaxf(m_r[r], mx);
        alpha[r] = exp2f((m_r[r] - mn) * L2E);
        m_r[r] = mn;
        float rs = 0.f;
#pragma unroll
        for (int n = 0; n < 4; ++n) {
            float p = exp2f((s[n][r] - mn) * L2E);
            s[n][r] = p;
            rs += p;
        }
        rs += __shfl_xor(rs, 1);
        rs += __shfl_xor(rs, 2);
        rs += __shfl_xor(rs, 4);
        rs += __shfl_xor(rs, 8);
        l_r[r] = l_r[r] * alpha[r] + rs;
    }
#pragma unroll
    for (int dn = 0; dn < 4; ++dn)
#pragma unroll
        for (int r = 0; r < 4; ++r) accy[dn][r] *= alpha[r];
    {
        int rowb = w * 16 + fq * 4;
#pragma unroll
        for (int n = 0; n < 4; ++n) {
            int key = n * 16 + fr;
            int s8 = key >> 3, kr = key & 7;
#pragma unroll
            for (int r = 0; r < 4; ++r) {
                int row = rowb + r;
                sP[row * 64 + (((s8 ^ (row & 7)) << 3) | kr)] = f2h(s[n][r]);
            }
        }
    }
    // P rows written & read by the same wave only (rows [16w,16w+16)): no barrier.
    f16x8 pa[2];
    {
        int prow = w * 16 + fr;
#pragma unroll
        for (int kk = 0; kk < 2; ++kk) {
            int sl = kk * 4 + fq;
            pa[kk] = *(const f16x8*)&sP[prow * 64 + ((sl ^ (prow & 7)) << 3)];
        }
    }
    __builtin_amdgcn_s_setprio(1);
#pragma unroll
    for (int dn = 0; dn < 4; ++dn) {
        int vrow = dn * 16 + fr;
#pragma unroll
        for (int kk = 0; kk < 2; ++kk) {
            int sl = kk * 4 + fq;
            f16x8 vb = *(const f16x8*)&sV[vrow * 64 + ((sl ^ (vrow & 7)) << 3)];
            accy[dn] = MFMAH(pa[kk], vb, accy[dn]);
        }
    }
    __builtin_amdgcn_s_setprio(0);
}

// Sequential paired q-tiles: block (bh,slot) processes qtA=15-slot fully,
// writes it out, then qtB=slot. Constant 17 steps/block -> grid 1024 = exactly
// the 4-blocks/CU x 256-CU residency: ONE generation, zero tail, perfect
// balance (round-4's simultaneous pairing doubled live registers -> spills;
// sequential keeps state identical to attn4). Double-buffered K/V, one
// barrier per step. XCD mapping: each XCD owns 16 heads = 4MB K/V = its L2.
__global__ __launch_bounds__(256) void attn5_kernel(const u16* __restrict__ qf, const u16* __restrict__ kf,
                                                    const u16* __restrict__ vt, u16* __restrict__ yb) {
    __shared__ u16 sK[2][4096], sV[2][4096], sP[4096];
    const int r8 = blockIdx.x & 7, j = blockIdx.x >> 3;   // 1024 blocks
    const int bh = r8 * 16 + (j >> 3);
    const int slot = j & 7;
    const int b = bh >> 4, h = bh & 15;
    const int tid = threadIdx.x, lane = tid & 63, w = tid >> 6;
    const int fr = lane & 15, fq = lane >> 4;
    const u16* kbase = kf + (size_t)bh * 65536;
    const u16* vbase = vt + (size_t)bh * 65536;

#pragma unroll
    for (int pass = 0; pass < 2; ++pass) {
        const int qt = pass ? slot : 15 - slot;
        // Stage Q through sP (wave-private rows) + K/V tile 0 into buffer 0.
        // All prior reads of sP/sK/sV were drained by the last barrier.
        stage64(qf + (size_t)bh * 65536 + qt * 4096, 64, sP, w, lane);
        stage64(kbase, 64, sK[0], w, lane);
        stage64(vbase, 1024, sV[0], w, lane);
        __syncthreads();   // drains DMA (compiler emits vmcnt(0) before s_barrier)
        f16x8 qfr[2];
        {
            int row = w * 16 + fr;
#pragma unroll
            for (int kk = 0; kk < 2; ++kk) {
                int sl = kk * 4 + fq;
                qfr[kk] = *(const f16x8*)&sP[row * 64 + ((sl ^ (row & 7)) << 3)];
            }
        }
        f32x4 accy[4] = {};
        float m_r[4], l_r[4];
#pragma unroll
        for (int r = 0; r < 4; ++r) { m_r[r] = -1e30f; l_r[r] = 0.f; }

        int cur = 0;
        for (int kt = 0; kt <= qt; ++kt) {
            if (kt < qt) {   // issue next tile's DMA before computing current
                stage64(kbase + (kt + 1) * 4096, 64, sK[cur ^ 1], w, lane);
                stage64(vbase + (kt + 1) * 64, 1024, sV[cur ^ 1], w, lane);
            }
            attn_step(qfr, accy, m_r, l_r, sK[cur], sV[cur], sP, kt == qt, w, lane);
            __syncthreads();  // drains this wave's DMA + orders buf[cur^1] reuse
            cur ^= 1;
        }
        {
            int rowbase = qt * 64 + w * 16 + fq * 4;
            int colb = h * 64 + fr;
#pragma unroll
            for (int r = 0; r < 4; ++r) {
                float inv = 1.0f / l_r[r];
#pragma unroll
                for (int dn = 0; dn < 4; ++dn)
                    yb[(size_t)(b * 1024 + rowbase + r) * 1024 + colb + dn * 16] = f2h(accy[dn][r] * inv);
            }
        }
    }
}

// ---------------- out projection: (8192x1024) x (1024x1024)^T, fp16 ----------------
__global__ __launch_bounds__(256) void proj_gemm2(const u16* __restrict__ yb, const u16* __restrict__ wpb,
                                                  float* __restrict__ out) {
    __shared__ u16 sA[8192], sB[8192];
    const int bid = blockIdx.x;
    const int swz = (bid & 7) * 64 + (bid >> 3);    // 512 = 8*64
    const int mb = swz >> 3, nb = swz & 7;
    const int m0 = mb * 128, n0 = nb * 128;
    const int tid = threadIdx.x, lane = tid & 63, w = tid >> 6;
    const int wr = w >> 1, wc = w & 1;
    const int fr = lane & 15, fq = lane >> 4;
    const u16* pa = yb + (size_t)m0 * 1024;
    const u16* pb = wpb + (size_t)n0 * 1024;
    f32x4 acc[4][4] = {};
    for (int k0 = 0; k0 < 1024; k0 += 64) {
        stage_tile(pa + k0, sA, w, lane);
        stage_tile(pb + k0, sB, w, lane);
        __syncthreads();
#pragma unroll
        for (int kk = 0; kk < 2; ++kk) {
            f16x8 af[4], bb[4];
#pragma unroll
            for (int m = 0; m < 4; ++m) {
                int row = wr * 64 + m * 16 + fr;
                af[m] = *(const f16x8*)&sA[row * 64 + ((((kk * 4 + fq)) ^ (fr & 7)) << 3)];
            }
#pragma unroll
            for (int n = 0; n < 4; ++n) {
                int row = wc * 64 + n * 16 + fr;
                bb[n] = *(const f16x8*)&sB[row * 64 + ((((kk * 4 + fq)) ^ (fr & 7)) << 3)];
            }
#pragma unroll
            for (int n = 0; n < 4; ++n)
#pragma unroll
                for (int m = 0; m < 4; ++m) acc[m][n] = MFMAH(af[m], bb[n], acc[m][n]);
        }
        __syncthreads();
    }
#pragma unroll
    for (int m = 0; m < 4; ++m) {
        int rowb = m0 + wr * 64 + m * 16 + fq * 4;
#pragma unroll
        for (int n = 0; n < 4; ++n) {
            int col = n0 + wc * 64 + n * 16 + fr;
#pragma unroll
            for (int r = 0; r < 4; ++r) out[(size_t)(rowb + r) * 1024 + col] = acc[m][n][r];
        }
    }
}

extern "C" void kernel_launch(void* const* d_in, const int* in_sizes, int n_in,
                              void* d_out, int out_size, void* d_ws, size_t ws_size,
                              hipStream_t stream) {
    const float* x  = (const float*)d_in[0];
    const float* Wa = (const float*)d_in[1];
    const float* Wp = (const float*)d_in[2];
    float* out = (float*)d_out;
    char* ws = (char*)d_ws;
    size_t off = 0;
    float* qkv = (float*)(ws + off); off += (size_t)8192 * 3072 * 4;   // 96 MB
    u16* xh  = (u16*)(ws + off); off += 16777216;
    u16* xl  = (u16*)(ws + off); off += 16777216;
    u16* wf  = (u16*)(ws + off); off += 6291456;
    u16* wpb = (u16*)(ws + off); off += 2097152;
    u16* qf  = (u16*)(ws + off); off += 16777216;
    u16* kf  = (u16*)(ws + off); off += 16777216;
    u16* vt  = (u16*)(ws + off); off += 16777216;
    u16* yb  = (u16*)(ws + off); off += 16777216;

    split16_kernel<<<8192, 256, 0, stream>>>(x, xh, xl, 8192 * 1024 / 4);
    cvt16_kernel<<<3072, 256, 0, stream>>>(Wa, wf, 3072 * 1024 / 4);
    cvt16_kernel<<<1024, 256, 0, stream>>>(Wp, wpb, 1024 * 1024 / 4);
    qkv_gemm2<<<1536, 256, 0, stream>>>(xh, xl, wf, qkv);
    rotary_kernel<<<32768, 256, 0, stream>>>(qkv, qf, kf, vt);
    attn5_kernel<<<1024, 256, 0, stream>>>(qf, kf, vt, yb);
    proj_gemm2<<<512, 256, 0, stream>>>(yb, wpb, out);
}